// Round 1
// baseline (411.400 us; speedup 1.0000x reference)
//
#include <hip/hip_runtime.h>
#include <hip/hip_bf16.h>

// SpatialTransformer bilinear warp, N=4 C=32 H=512 W=512, fp32.
// One thread per output pixel (n,h,w); weights computed once, reused
// across all C=32 channels. Tap validity folded into weights (branchless).

constexpr int N_ = 4, C_ = 32, H_ = 512, W_ = 512;

__global__ __launch_bounds__(256) void st_warp_kernel(
    const float* __restrict__ src, const float* __restrict__ flow,
    float* __restrict__ out) {
    int idx = blockIdx.x * blockDim.x + threadIdx.x;   // over N*H*W
    if (idx >= N_ * H_ * W_) return;

    int w = idx & (W_ - 1);
    int h = (idx >> 9) & (H_ - 1);
    int n = idx >> 18;

    const size_t plane = (size_t)H_ * W_;
    const float* f = flow + (size_t)n * 2 * plane + (size_t)h * W_ + w;
    float fx = f[0];
    float fy = f[plane];

    // replicate reference math exactly (normalize -> unnormalize round-trip)
    float xl = (float)w + fx;
    float yl = (float)h + fy;
    float xn = 2.0f * (xl / (float)(W_ - 1) - 0.5f);
    float yn = 2.0f * (yl / (float)(H_ - 1) - 0.5f);
    float x = (xn + 1.0f) / 2.0f * (float)(W_ - 1);
    float y = (yn + 1.0f) / 2.0f * (float)(H_ - 1);

    float x0f = floorf(x), y0f = floorf(y);
    float x1f = x0f + 1.0f, y1f = y0f + 1.0f;

    int ix0 = (int)x0f, iy0 = (int)y0f;

    // padded-clamp semantics: index into pad-by-1 image, clamped to [0, W+1],
    // then shifted back; tap is zero unless it lands inside the real image.
    int xa = min(max(ix0 + 1, 0), W_ + 1) - 1;   // [-1, W]
    int xb = min(max(ix0 + 2, 0), W_ + 1) - 1;
    int ya = min(max(iy0 + 1, 0), H_ + 1) - 1;
    int yb = min(max(iy0 + 2, 0), H_ + 1) - 1;

    float vxa = ((unsigned)xa < (unsigned)W_) ? 1.0f : 0.0f;
    float vxb = ((unsigned)xb < (unsigned)W_) ? 1.0f : 0.0f;
    float vya = ((unsigned)ya < (unsigned)H_) ? 1.0f : 0.0f;
    float vyb = ((unsigned)yb < (unsigned)H_) ? 1.0f : 0.0f;

    float ax = (x1f - x) * vxa;   // x-weight for x0 taps
    float bx = (x - x0f) * vxb;   // x-weight for x1 taps
    float ay = (y1f - y) * vya;
    float by = (y - y0f) * vyb;

    float wa = ax * ay;   // (x0,y0)
    float wb = ax * by;   // (x0,y1)
    float wc = bx * ay;   // (x1,y0)
    float wd = bx * by;   // (x1,y1)

    // clamp addresses for safety (weight already zero when invalid)
    int xac = min(max(xa, 0), W_ - 1);
    int xbc = min(max(xb, 0), W_ - 1);
    int yac = min(max(ya, 0), H_ - 1);
    int ybc = min(max(yb, 0), H_ - 1);

    int o00 = yac * W_ + xac;
    int o01 = ybc * W_ + xac;
    int o10 = yac * W_ + xbc;
    int o11 = ybc * W_ + xbc;

    const float* sp = src + (size_t)n * C_ * plane;
    float* op = out + (size_t)n * C_ * plane + (size_t)h * W_ + w;

    #pragma unroll 4
    for (int c = 0; c < C_; ++c) {
        const float* s = sp + (size_t)c * plane;
        float v = s[o00] * wa + s[o01] * wb + s[o10] * wc + s[o11] * wd;
        op[(size_t)c * plane] = v;
    }
}

extern "C" void kernel_launch(void* const* d_in, const int* in_sizes, int n_in,
                              void* d_out, int out_size, void* d_ws, size_t ws_size,
                              hipStream_t stream) {
    const float* src  = (const float*)d_in[0];
    const float* flow = (const float*)d_in[1];
    float* out = (float*)d_out;

    int total = N_ * H_ * W_;            // 1,048,576 threads
    int block = 256;
    int grid = (total + block - 1) / block;   // 4096 blocks
    st_warp_kernel<<<grid, block, 0, stream>>>(src, flow, out);
}

// Round 2
// 317.097 us; speedup vs baseline: 1.2974x; 1.2974x over previous
//
#include <hip/hip_runtime.h>
#include <hip/hip_bf16.h>

// SpatialTransformer bilinear warp, N=4 C=32 H=512 W=512, fp32.
// Round 2: NCHW gather was TA-transaction-bound (1.87 TB/s, 255 us).
// Fix: pass 1 transposes src -> NHWC in d_ws; pass 2 gathers with
// 8 lanes/pixel x float4 (128B contiguous per tap), writes NCHW directly.

constexpr int N_ = 4, C_ = 32, H_ = 512, W_ = 512;
constexpr size_t PLANE = (size_t)H_ * W_;

// ---------------- Pass 1: NCHW -> NHWC transpose ----------------
// Per block: one batch n, 256 consecutive pixels, all 32 channels.
// Load coalesced along pixels, LDS-stage, store coalesced along channels.
__global__ __launch_bounds__(256) void nchw_to_nhwc(
    const float* __restrict__ in, float* __restrict__ out) {
    __shared__ float lds[256][33];   // [pixel][channel], pad to kill conflicts

    int b = blockIdx.x;              // 4096 blocks: n = b>>10, pixel chunk = b&1023
    int n = b >> 10;
    int pb = (b & 1023) << 8;        // pixel base within plane

    int t = threadIdx.x;

    // load: 8 float4 per thread, coalesced along pixels
    {
        int c = t >> 3;              // 0..31
        int j = t & 7;               // 0..7
        const float* ip = in + ((size_t)n * C_ + c) * PLANE + pb;
        #pragma unroll
        for (int it = 0; it < 8; ++it) {
            int p_off = it * 32 + j * 4;
            float4 v = *(const float4*)(ip + p_off);
            lds[p_off + 0][c] = v.x;
            lds[p_off + 1][c] = v.y;
            lds[p_off + 2][c] = v.z;
            lds[p_off + 3][c] = v.w;
        }
    }
    __syncthreads();

    // store: 8 float4 per thread, coalesced along (pixel*32 + c)
    {
        int q = t & 7;               // channel quad 0..7
        int u = t >> 3;              // 0..31
        float* op = out + ((size_t)n * PLANE + pb) * C_;
        #pragma unroll
        for (int it = 0; it < 8; ++it) {
            int p_local = it * 32 + u;
            float4 v;
            v.x = lds[p_local][q * 4 + 0];
            v.y = lds[p_local][q * 4 + 1];
            v.z = lds[p_local][q * 4 + 2];
            v.w = lds[p_local][q * 4 + 3];
            *(float4*)(op + (size_t)p_local * C_ + q * 4) = v;
        }
    }
}

// ---------------- Pass 2: warp from NHWC, write NCHW ----------------
// 8 threads per pixel; thread handles channel quad q (4 channels).
// Each tap read = 8 lanes x float4 = 128B contiguous.
__global__ __launch_bounds__(256) void st_warp_nhwc(
    const float* __restrict__ srcT, const float* __restrict__ flow,
    float* __restrict__ out) {
    int t = blockIdx.x * blockDim.x + threadIdx.x;   // 8M threads
    int q = t & 7;           // channel quad
    int g = t >> 3;          // global pixel index, 0 .. N*PLANE-1

    int w = g & (W_ - 1);
    int h = (g >> 9) & (H_ - 1);
    int n = g >> 18;

    const float* f = flow + (size_t)n * 2 * PLANE + (size_t)h * W_ + w;
    float fx = f[0];
    float fy = f[PLANE];

    // replicate reference math exactly
    float xl = (float)w + fx;
    float yl = (float)h + fy;
    float xn = 2.0f * (xl / (float)(W_ - 1) - 0.5f);
    float yn = 2.0f * (yl / (float)(H_ - 1) - 0.5f);
    float x = (xn + 1.0f) / 2.0f * (float)(W_ - 1);
    float y = (yn + 1.0f) / 2.0f * (float)(H_ - 1);

    float x0f = floorf(x), y0f = floorf(y);
    float x1f = x0f + 1.0f, y1f = y0f + 1.0f;

    int ix0 = (int)x0f, iy0 = (int)y0f;

    int xa = min(max(ix0 + 1, 0), W_ + 1) - 1;   // [-1, W]
    int xb = min(max(ix0 + 2, 0), W_ + 1) - 1;
    int ya = min(max(iy0 + 1, 0), H_ + 1) - 1;
    int yb = min(max(iy0 + 2, 0), H_ + 1) - 1;

    float vxa = ((unsigned)xa < (unsigned)W_) ? 1.0f : 0.0f;
    float vxb = ((unsigned)xb < (unsigned)W_) ? 1.0f : 0.0f;
    float vya = ((unsigned)ya < (unsigned)H_) ? 1.0f : 0.0f;
    float vyb = ((unsigned)yb < (unsigned)H_) ? 1.0f : 0.0f;

    float ax = (x1f - x) * vxa;
    float bx = (x - x0f) * vxb;
    float ay = (y1f - y) * vya;
    float by = (y - y0f) * vyb;

    float wa = ax * ay;   // (x0,y0)
    float wb = ax * by;   // (x0,y1)
    float wc = bx * ay;   // (x1,y0)
    float wd = bx * by;   // (x1,y1)

    int xac = min(max(xa, 0), W_ - 1);
    int xbc = min(max(xb, 0), W_ - 1);
    int yac = min(max(ya, 0), H_ - 1);
    int ybc = min(max(yb, 0), H_ - 1);

    const float* sp = srcT + (size_t)n * PLANE * C_ + (size_t)q * 4;
    const float4 A = *(const float4*)(sp + (size_t)(yac * W_ + xac) * C_);
    const float4 B = *(const float4*)(sp + (size_t)(ybc * W_ + xac) * C_);
    const float4 Cv = *(const float4*)(sp + (size_t)(yac * W_ + xbc) * C_);
    const float4 D = *(const float4*)(sp + (size_t)(ybc * W_ + xbc) * C_);

    float r0 = A.x * wa + B.x * wb + Cv.x * wc + D.x * wd;
    float r1 = A.y * wa + B.y * wb + Cv.y * wc + D.y * wd;
    float r2 = A.z * wa + B.z * wb + Cv.z * wc + D.z * wd;
    float r3 = A.w * wa + B.w * wb + Cv.w * wc + D.w * wd;

    float* op = out + ((size_t)n * C_ + 4 * q) * PLANE + (size_t)h * W_ + w;
    op[0] = r0;
    op[PLANE] = r1;
    op[2 * PLANE] = r2;
    op[3 * PLANE] = r3;
}

// ---------------- Fallback (round-1 direct kernel) ----------------
__global__ __launch_bounds__(256) void st_warp_direct(
    const float* __restrict__ src, const float* __restrict__ flow,
    float* __restrict__ out) {
    int idx = blockIdx.x * blockDim.x + threadIdx.x;
    if (idx >= N_ * H_ * W_) return;
    int w = idx & (W_ - 1);
    int h = (idx >> 9) & (H_ - 1);
    int n = idx >> 18;
    const float* f = flow + (size_t)n * 2 * PLANE + (size_t)h * W_ + w;
    float fx = f[0], fy = f[PLANE];
    float xl = (float)w + fx, yl = (float)h + fy;
    float xn = 2.0f * (xl / (float)(W_ - 1) - 0.5f);
    float yn = 2.0f * (yl / (float)(H_ - 1) - 0.5f);
    float x = (xn + 1.0f) / 2.0f * (float)(W_ - 1);
    float y = (yn + 1.0f) / 2.0f * (float)(H_ - 1);
    float x0f = floorf(x), y0f = floorf(y);
    float x1f = x0f + 1.0f, y1f = y0f + 1.0f;
    int ix0 = (int)x0f, iy0 = (int)y0f;
    int xa = min(max(ix0 + 1, 0), W_ + 1) - 1;
    int xb = min(max(ix0 + 2, 0), W_ + 1) - 1;
    int ya = min(max(iy0 + 1, 0), H_ + 1) - 1;
    int yb = min(max(iy0 + 2, 0), H_ + 1) - 1;
    float vxa = ((unsigned)xa < (unsigned)W_) ? 1.0f : 0.0f;
    float vxb = ((unsigned)xb < (unsigned)W_) ? 1.0f : 0.0f;
    float vya = ((unsigned)ya < (unsigned)H_) ? 1.0f : 0.0f;
    float vyb = ((unsigned)yb < (unsigned)H_) ? 1.0f : 0.0f;
    float ax = (x1f - x) * vxa, bx = (x - x0f) * vxb;
    float ay = (y1f - y) * vya, by = (y - y0f) * vyb;
    float wa = ax * ay, wb = ax * by, wc = bx * ay, wd = bx * by;
    int xac = min(max(xa, 0), W_ - 1), xbc = min(max(xb, 0), W_ - 1);
    int yac = min(max(ya, 0), H_ - 1), ybc = min(max(yb, 0), H_ - 1);
    int o00 = yac * W_ + xac, o01 = ybc * W_ + xac;
    int o10 = yac * W_ + xbc, o11 = ybc * W_ + xbc;
    const float* sp = src + (size_t)n * C_ * PLANE;
    float* op = out + (size_t)n * C_ * PLANE + (size_t)h * W_ + w;
    #pragma unroll 4
    for (int c = 0; c < C_; ++c) {
        const float* s = sp + (size_t)c * PLANE;
        float v = s[o00] * wa + s[o01] * wb + s[o10] * wc + s[o11] * wd;
        op[(size_t)c * PLANE] = v;
    }
}

extern "C" void kernel_launch(void* const* d_in, const int* in_sizes, int n_in,
                              void* d_out, int out_size, void* d_ws, size_t ws_size,
                              hipStream_t stream) {
    const float* src  = (const float*)d_in[0];
    const float* flow = (const float*)d_in[1];
    float* out = (float*)d_out;

    const size_t need = (size_t)N_ * C_ * PLANE * sizeof(float);  // 128 MiB
    if (ws_size >= need) {
        float* srcT = (float*)d_ws;
        nchw_to_nhwc<<<4096, 256, 0, stream>>>(src, srcT);
        int total = N_ * H_ * W_ * 8;                 // 8 threads / pixel
        st_warp_nhwc<<<total / 256, 256, 0, stream>>>(srcT, flow, out);
    } else {
        int total = N_ * H_ * W_;
        st_warp_direct<<<(total + 255) / 256, 256, 0, stream>>>(src, flow, out);
    }
}